// Round 5
// baseline (121.625 us; speedup 1.0000x reference)
//
#include <hip/hip_runtime.h>
#include <math.h>

typedef _Float16 f16;
typedef _Float16 f16x4 __attribute__((ext_vector_type(4)));
typedef _Float16 f16x8 __attribute__((ext_vector_type(8)));
typedef __bf16 bf16x4 __attribute__((ext_vector_type(4)));
typedef __bf16 bf16x4a8 __attribute__((ext_vector_type(4), aligned(8)));
typedef short s16x4 __attribute__((ext_vector_type(4)));
typedef float f32x4 __attribute__((ext_vector_type(4)));
typedef unsigned int u32;

#define MFMA_F16(a, b, c)  __builtin_amdgcn_mfma_f32_16x16x32_f16(a, b, c, 0, 0, 0)
#define MFMA_BF16_K16(a, b, c) __builtin_amdgcn_mfma_f32_16x16x16bf16_1k(a, b, c, 0, 0, 0)

static __device__ inline f16x8 cvt8(const float* p) {
    const float4* p4 = (const float4*)p;
    float4 u0 = p4[0], u1 = p4[1];
    f16x8 r;
    r[0] = (f16)u0.x; r[1] = (f16)u0.y; r[2] = (f16)u0.z; r[3] = (f16)u0.w;
    r[4] = (f16)u1.x; r[5] = (f16)u1.y; r[6] = (f16)u1.z; r[7] = (f16)u1.w;
    return r;
}

static __device__ inline u32 alignsel(u32 hi, u32 lo, u32 sh) {
    return sh ? (u32)(((((unsigned long long)hi) << 32) | lo) >> sh) : lo;
}

static __device__ inline u32 pack2bf(float a, float b) {
    __bf16 x0 = (__bf16)a, x1 = (__bf16)b;
    return (u32)__builtin_bit_cast(unsigned short, x0) |
           ((u32)__builtin_bit_cast(unsigned short, x1) << 16);
}

// ---------------------------------------------------------------------------
// Fused producer. Blocks 0..1215: (b,g,hp) rows -> Q,K,V via f16 MFMA;
// block 1216 builds the two small rel tables.
// R5 changes: V4 (4 shifted copies) replaced by linear Vb bf16
//   [bg][hp][c][wp44] (rows 88 B) written straight from vt.
// rel tables: Trh f16 [g][kh][c16] at relp[0..895]  (rel_h, kw-independent)
//             Trw f16 [g][kw8][c32] at relp[896..2943] (c<16 zero, kw=7 zero)
// ---------------------------------------------------------------------------
__global__ __launch_bounds__(256) void produce_kernel(
    const float* __restrict__ x,
    const float* __restrict__ wq, const float* __restrict__ bq,
    const float* __restrict__ wk, const float* __restrict__ bk,
    const float* __restrict__ wv, const float* __restrict__ bv,
    const float* __restrict__ rel_h, const float* __restrict__ rel_w,
    f16* __restrict__ Qb, f16* __restrict__ Kb,
    __bf16* __restrict__ Vb, f16* __restrict__ relp) {
    int bid = blockIdx.x;
    int t = threadIdx.x;

    if (bid == 1216) {  // rel tables
        for (int idx = t; idx < 2944; idx += 256) {
            float v;
            if (idx < 896) {           // Trh[(g*7+kh)*16 + c] = rel_h[c][g*7+kh]
                int c = idx & 15, gk = idx >> 4;
                v = rel_h[c * 56 + gk];
            } else {                   // Trw[(g*8+kw)*32 + c]
                int i2 = idx - 896;
                int c = i2 & 31, gw = i2 >> 5;
                int g = gw >> 3, kw = gw & 7;
                v = (c >= 16 && kw < 7) ? rel_w[(c - 16) * 56 + g * 7 + kw] : 0.f;
            }
            relp[idx] = (f16)v;
        }
        return;
    }

    int hp = bid % 38, g = (bid / 38) & 7, b = bid / 304;
    bool hin = (hp >= 3 && hp < 35);
    size_t kvbase = (size_t)(b * 8 + g);
    u32* Vb32 = (u32*)Vb;

    if (!hin) {  // pure-bias row (h padding)
        for (int idx = t; idx < 38 * 32; idx += 256) {
            int wp = idx >> 5, c = idx & 31;
            Kb[((kvbase * 38 + hp) * 38 + wp) * 32 + c] = (f16)bk[g * 32 + c];
        }
        for (int idx = t; idx < 704; idx += 256) {  // 32 c * 22 dwords
            int c = idx / 22, dw = idx - c * 22;
            float bb = bv[g * 32 + c];
            float v0 = (dw * 2 <= 37) ? bb : 0.f;
            float v1 = (dw * 2 + 1 <= 37) ? bb : 0.f;
            Vb32[((kvbase * 38 + hp) * 32 + c) * 22 + dw] = pack2bf(v0, v1);
        }
        return;
    }

    int h = hp - 3;
    __shared__ __align__(16) f16 xTl[32 * 40];   // [w][ic], stride 40
    __shared__ float vt[32 * 44];                // [c][wp], wp 0..43 (>=38 zero)

    {   // stage x^T (each thread one float4 along w)
        int ic = t >> 3, w = (t & 7) * 4;
        float4 xv = *(const float4*)(x + (((size_t)b * 256 + g * 32 + ic) * 32 + h) * 32 + w);
        xTl[(w + 0) * 40 + ic] = (f16)xv.x;
        xTl[(w + 1) * 40 + ic] = (f16)xv.y;
        xTl[(w + 2) * 40 + ic] = (f16)xv.z;
        xTl[(w + 3) * 40 + ic] = (f16)xv.w;
    }
    // vt borders: wp {0,1,2,35,36,37} = bias; wp 38..43 = 0
    for (int idx = t; idx < 384; idx += 256) {
        int c = idx & 31, wi = idx >> 5;  // wi 0..11
        float bb = bv[g * 32 + c];
        if (wi < 3) vt[c * 44 + wi] = bb;                 // 0,1,2
        else if (wi < 6) vt[c * 44 + 32 + wi] = bb;       // 35,36,37
        else vt[c * 44 + 32 + wi] = 0.f;                  // 38..43
    }
    __syncthreads();

    int l15 = t & 15, quad = (t >> 4) & 3, wave = t >> 6;

    f16x8 xf0 = *(const f16x8*)(xTl + l15 * 40 + quad * 8);
    f16x8 xf1 = *(const f16x8*)(xTl + (16 + l15) * 40 + quad * 8);

    // ---- Q ----
#pragma unroll
    for (int i = 0; i < 2; ++i) {
        int mq = wave * 2 + i;
        f16x8 wf = cvt8(wq + ((size_t)g * 128 + mq * 16 + l15) * 32 + quad * 8);
        float4 b4 = *(const float4*)(bq + g * 128 + mq * 16 + quad * 4);
#pragma unroll
        for (int Nt = 0; Nt < 2; ++Nt) {
            f32x4 d = {0.f, 0.f, 0.f, 0.f};
            d = MFMA_F16(wf, Nt ? xf1 : xf0, d);
            f16x4 q4;
            q4[0] = (f16)(d[0] + b4.x); q4[1] = (f16)(d[1] + b4.y);
            q4[2] = (f16)(d[2] + b4.z); q4[3] = (f16)(d[3] + b4.w);
            int w = Nt * 16 + l15;
            *(f16x4*)(Qb + (size_t)((b * 32 + h) * 32 + w) * 1024 + g * 128 + mq * 16 + quad * 4) = q4;
        }
    }

    if (wave < 2) {
        // ---- K ----
        f16x8 wf = cvt8(wk + ((size_t)g * 32 + wave * 16 + l15) * 32 + quad * 8);
        float4 b4 = *(const float4*)(bk + g * 32 + wave * 16 + quad * 4);
#pragma unroll
        for (int Nt = 0; Nt < 2; ++Nt) {
            f32x4 d = {0.f, 0.f, 0.f, 0.f};
            d = MFMA_F16(wf, Nt ? xf1 : xf0, d);
            f16x4 k4;
            k4[0] = (f16)(d[0] + b4.x); k4[1] = (f16)(d[1] + b4.y);
            k4[2] = (f16)(d[2] + b4.z); k4[3] = (f16)(d[3] + b4.w);
            int wp = Nt * 16 + l15 + 3;
            *(f16x4*)(Kb + ((kvbase * 38 + hp) * 38 + wp) * 32 + wave * 16 + quad * 4) = k4;
        }
    } else {
        // ---- V -> LDS vt ----
        int Nt = wave - 2;
        f16x8 wf = cvt8(wv + ((size_t)g * 32 + Nt * 16 + l15) * 32 + quad * 8);
        float bias = bv[g * 32 + Nt * 16 + l15];
        int c = Nt * 16 + l15;
#pragma unroll
        for (int Mt = 0; Mt < 2; ++Mt) {
            f32x4 d = {0.f, 0.f, 0.f, 0.f};
            d = MFMA_F16(Mt ? xf1 : xf0, wf, d);
            int wp0 = Mt * 16 + quad * 4 + 3;
            vt[c * 44 + wp0 + 0] = d[0] + bias;
            vt[c * 44 + wp0 + 1] = d[1] + bias;
            vt[c * 44 + wp0 + 2] = d[2] + bias;
            vt[c * 44 + wp0 + 3] = d[3] + bias;
        }
    }

    // ---- Kb wp borders (bias) ----
    for (int idx = t; idx < 192; idx += 256) {
        int wi = idx >> 5, c = idx & 31;
        int wp = (wi < 3) ? wi : (32 + wi);  // {0,1,2,35,36,37}
        Kb[((kvbase * 38 + hp) * 38 + wp) * 32 + c] = (f16)bk[g * 32 + c];
    }
    __syncthreads();

    // ---- Vb write: [bg][hp][c][wp44], rows 88 B, from vt ----
    for (int idx = t; idx < 704; idx += 256) {
        int c = idx / 22, dw = idx - c * 22;
        Vb32[((kvbase * 38 + hp) * 32 + c) * 22 + dw] =
            pack2bf(vt[c * 44 + dw * 2], vt[c * 44 + dw * 2 + 1]);
    }
}

// ---------------------------------------------------------------------------
// MFMA attention, R5: block = (b, x, y-octet), 8 waves, each wave owns one
// position fully (4 chunks x 7 kh). K-window (+rel_h pre-added) and V-window
// staged in LDS once per block; rel_w = 4 KB LDS table read once per chunk.
// Cuts L2 traffic ~700 MB -> ~90 MB. Fragment math identical to verified
// baseline; only data sources changed.
// LDS: Klds 840 rows x 80 B = 67.2 KB; Vlds 1792 rows x 40 B = 71.7 KB;
//      Trw 4 KB. Total 143 KB -> 1 block/CU.
// ---------------------------------------------------------------------------
__global__ __launch_bounds__(512, 1) void attn_kernel(
    const f16* __restrict__ Qb, const f16* __restrict__ Kb,
    const __bf16* __restrict__ Vb, const f16* __restrict__ relp,
    float* __restrict__ out) {
    __shared__ __align__(16) f16 Klds[33600];     // [g][kh][wpl15][c32], row pad 40 f16 (80 B)
    __shared__ __align__(16) __bf16 Vlds[35840];  // [g][kh][c32][wpw], row pad 20 bf16 (40 B)
    __shared__ __align__(16) f16 Trw_l[2048];     // [g][kw8][c32]

    int bid = blockIdx.x;
    int t = threadIdx.x;
    int G = (bid & 7) * 64 + (bid >> 3);  // XCD swizzle: same (b,x) -> same XCD
    int yq = G & 3, x = (G >> 2) & 31, b = G >> 7;
    int y0 = yq * 8;
    int b8 = b * 8;

    int wvi = t >> 6;        // wave = position y0 + wvi
    int lane = t & 63;
    int l15 = lane & 15, quad = lane >> 4, kwl = lane & 7, p8 = (lane >> 3) & 1;
    bool oddq = (quad & 1);
    int y = y0 + wvi;
    int pid = (b * 32 + x) * 32 + y;

    // Q fragments (issue before staging; independent of LDS)
    f16x8 qf[2];
    {
        const f16* qp = Qb + (size_t)pid * 1024;
        qf[0] = *(const f16x8*)(qp + l15 * 32 + quad * 8);
        qf[1] = *(const f16x8*)(qp + (16 + l15) * 32 + quad * 8);
    }

    // ---- stage K window (+ rel_h into c<16) : 840 rows x 4 quads ----
    for (int i = t; i < 3360; i += 512) {
        int row = i >> 2, q = i & 3;
        int g = row / 105, r2 = row - g * 105;
        int kh = r2 / 15, wpl = r2 - kh * 15;
        int wp = y0 + wpl; if (wp > 37) wp = 37;
        f16x8 kv = *(const f16x8*)(Kb + (((size_t)(b8 + g) * 38 + x + kh) * 38 + wp) * 32 + q * 8);
        if (q < 2) kv += *(const f16x8*)(relp + (g * 7 + kh) * 16 + q * 8);
        *(f16x8*)(Klds + row * 40 + q * 8) = kv;
    }
    // ---- stage V window: 1792 rows x 5 x 8B (elems y0 .. y0+19) ----
    for (int i = t; i < 8960; i += 512) {
        int row = i / 5, j = i - row * 5;   // row = (g*7+kh)*32 + c
        int g = row / 224, r2 = row - g * 224;
        int kh = r2 >> 5, c = r2 & 31;
        uint2 v = *(const uint2*)(Vb + (((size_t)(b8 + g) * 38 + x + kh) * 32 + c) * 44 + y0 + j * 4);
        *(uint2*)(Vlds + row * 20 + j * 4) = v;
    }
    // ---- stage rel_w table (4 KB) ----
    {
        int i = t;  // 512 threads x 8 B = 4 KB
        *(uint2*)(Trw_l + i * 4) = *(const uint2*)(relp + 896 + i * 4);
    }
    __syncthreads();

    float fsumT[2] = {0.f, 0.f};
    f32x4 acc[2][2];
#pragma unroll
    for (int ct = 0; ct < 2; ++ct)
#pragma unroll
        for (int m = 0; m < 2; ++m) acc[ct][m] = (f32x4){0.f, 0.f, 0.f, 0.f};

    // per-lane constants
    int wpl37 = 37 - y0;
    int wplk = wvi + kwl; if (wplk > wpl37) wplk = wpl37;   // clamp only hits kwl=7 junk slot
    u32 shsel = (wvi & 1) ? 16u : 0u;
    bool hi4 = (wvi & 2) != 0;
    int eA = ((quad & 1) + (wvi >> 2)) * 4;  // aligned window start (bf16 elems)

#pragma unroll
    for (int chunk = 0; chunk < 4; ++chunk) {
        int gpr = chunk * 2 + p8;
        int gpv = chunk * 2 + (quad >> 1);
        f16x8 rp = *(const f16x8*)(Trw_l + (gpr * 8 + kwl) * 32 + quad * 8);  // loop-invariant
        const f16* kp = Klds + (gpr * 105 + wplk) * 40 + quad * 8;
        const __bf16* vb0 = Vlds + (size_t)gpv * 4480 + l15 * 20 + eA;
        const __bf16* vb1 = vb0 + 320;  // c + 16
#pragma unroll
        for (int kh = 0; kh < 7; ++kh) {
            f16x8 kb = *(const f16x8*)kp;  kp += 600;
            kb += rp;  // K' = K + rel_h(staged) + rel_w
            uint2 A0 = *(const uint2*)vb0;
            uint2 B0 = *(const uint2*)(vb0 + 4);
            uint2 A1 = *(const uint2*)vb1;
            uint2 B1 = *(const uint2*)(vb1 + 4);
            vb0 += 640; vb1 += 640;
            u32 a0 = hi4 ? A0.y : A0.x, a1 = hi4 ? B0.x : A0.y, a2 = hi4 ? B0.y : B0.x;
            s16x4 vf0 = __builtin_bit_cast(s16x4,
                make_uint2(alignsel(a1, a0, shsel), alignsel(a2, a1, shsel)));
            u32 c0 = hi4 ? A1.y : A1.x, c1 = hi4 ? B1.x : A1.y, c2 = hi4 ? B1.y : B1.x;
            s16x4 vf1 = __builtin_bit_cast(s16x4,
                make_uint2(alignsel(c1, c0, shsel), alignsel(c2, c1, shsel)));
#pragma unroll
            for (int Mt = 0; Mt < 2; ++Mt) {
                f32x4 d = {0.f, 0.f, 0.f, 0.f};
                d = MFMA_F16(kb, qf[Mt], d);  // S^T: rows=keys, cols=qi
                float e0 = __expf(d[0]);
                float e1 = __expf(d[1]);
                float e2 = __expf(d[2]);
                float e3 = oddq ? 0.f : __expf(d[3]);  // kw=7 mask
                fsumT[Mt] += (e0 + e1) + (e2 + e3);
                bf16x4 pb;
                pb[0] = (__bf16)e0; pb[1] = (__bf16)e1;
                pb[2] = (__bf16)e2; pb[3] = (__bf16)e3;
                s16x4 pbi = __builtin_bit_cast(s16x4, pb);
                acc[0][Mt] = MFMA_BF16_K16(vf0, pbi, acc[0][Mt]);
                acc[1][Mt] = MFMA_BF16_K16(vf1, pbi, acc[1][Mt]);
            }
        }
    }

    // ---- fsum reduce across quads (each lane's keys are a quad-slice) ----
#pragma unroll
    for (int m = 0; m < 2; ++m) {
        fsumT[m] += __shfl_xor(fsumT[m], 16);
        fsumT[m] += __shfl_xor(fsumT[m], 32);
    }
    float inv[2] = {1.0f / fsumT[0], 1.0f / fsumT[1]};

    // ---- epilogue: normalize, head-sum over l15&3, write this wave's y ----
#pragma unroll
    for (int Mt = 0; Mt < 2; ++Mt)
#pragma unroll
        for (int ct = 0; ct < 2; ++ct) {
            float v[4];
#pragma unroll
            for (int r = 0; r < 4; ++r) {
                v[r] = acc[ct][Mt][r] * inv[Mt];
                v[r] += __shfl_xor(v[r], 1);
                v[r] += __shfl_xor(v[r], 2);
            }
            if ((l15 & 3) == 0) {
                int g = Mt * 4 + (l15 >> 2);
                float4 o4 = {v[0], v[1], v[2], v[3]};
                *(float4*)(out + ((((size_t)(b8 + g) * 32 + x) * 32 + y) << 5) +
                           ct * 16 + quad * 4) = o4;
            }
        }
}

// ---------------------------------------------------------------------------
extern "C" void kernel_launch(void* const* d_in, const int* in_sizes, int n_in,
                              void* d_out, int out_size, void* d_ws, size_t ws_size,
                              hipStream_t stream) {
    const float* x     = (const float*)d_in[0];
    const float* wq    = (const float*)d_in[1];
    const float* bq    = (const float*)d_in[2];
    const float* wk    = (const float*)d_in[3];
    const float* bk    = (const float*)d_in[4];
    const float* wv    = (const float*)d_in[5];
    const float* bv    = (const float*)d_in[6];
    const float* rel_h = (const float*)d_in[7];
    const float* rel_w = (const float*)d_in[8];
    float* out = (float*)d_out;

    // ws layout (bytes):
    //   Qb  f16 : 4096*1024*2        = 8,388,608
    //   Kb  f16 : 4*8*38*38*32*2     = 2,957,312
    //   Vb  bf16: 32*38*32*44*2      = 3,424,256
    //   relp f16: 2944*2             = 5,888
    unsigned char* ws = (unsigned char*)d_ws;
    f16*    Qb   = (f16*)ws;
    f16*    Kb   = (f16*)(ws + 8388608);
    __bf16* Vb   = (__bf16*)(ws + 8388608 + 2957312);
    f16*    relp = (f16*)(ws + 8388608 + 2957312 + 3424256);

    hipLaunchKernelGGL(produce_kernel, dim3(1217), dim3(256), 0, stream,
                       x, wq, bq, wk, bk, wv, bv, rel_h, rel_w, Qb, Kb, Vb, relp);
    hipLaunchKernelGGL(attn_kernel, dim3(512), dim3(512), 0, stream,
                       Qb, Kb, Vb, relp, out);
}